// Round 6
// baseline (161.358 us; speedup 1.0000x reference)
//
#include <hip/hip_runtime.h>

// Attention: B=8, N=4096, D=64, fp32 in/out, causal + padding mask.
// R6: barrier-free k-loop. prep writes K/V as bf16 in MFMA-fragment order;
//     waves stream fragments register-direct from L2 (no LDS staging, no
//     __syncthreads in loop), double-buffered in registers. 32x32x16 MFMA
//     (2x FLOP per fragment byte). P reaches PV via 8 shfl_xor(32) -- no
//     LDS round-trip. Grid: b=id&7 (batch<->XCD L2 affinity), co-resident
//     blocks get adjacent qb so both stay busy for the full serial chain.

#define BATCH 8
#define SEQ   4096
#define DIM   64
#define NKT   (SEQ / 64)

typedef __attribute__((ext_vector_type(8)))  short bf16x8;
typedef __attribute__((ext_vector_type(4)))  float f32x4;
typedef __attribute__((ext_vector_type(16))) float f32x16;

__device__ inline short f2bf(float f) {
    unsigned u = __builtin_bit_cast(unsigned, f);
    u += 0x7FFFu + ((u >> 16) & 1u);   // RNE
    return (short)(u >> 16);
}
__device__ inline unsigned pk2bf(float a, float b) {
    unsigned ua = __builtin_bit_cast(unsigned, a) + 0x8000u;
    unsigned ub = __builtin_bit_cast(unsigned, b) + 0x8000u;
    return __builtin_amdgcn_perm(ub, ua, 0x07060302u);
}
__device__ inline float fast_exp2(float x) {
#if __has_builtin(__builtin_amdgcn_exp2f)
    return __builtin_amdgcn_exp2f(x);
#else
    return exp2f(x);
#endif
}
__device__ inline bf16x8 pack8(const float4& a, const float4& b) {
    bf16x8 r;
    r[0] = f2bf(a.x); r[1] = f2bf(a.y); r[2] = f2bf(a.z); r[3] = f2bf(a.w);
    r[4] = f2bf(b.x); r[5] = f2bf(b.y); r[6] = f2bf(b.z); r[7] = f2bf(b.w);
    return r;
}

// ---- pre-pass: fp32 K,V -> bf16 in MFMA-fragment order ----
// K tile: cell(dchunk 0..7, key 0..63) = dchunk*64+key, 8 shorts (d in chunk)
// V tile: cell(kchunk 0..7, d 0..63)  = kchunk*64+d,   8 shorts (key in chunk)
__global__ __launch_bounds__(256)
void prep_kv(const float* __restrict__ kg, const float* __restrict__ vg,
             short* __restrict__ kw, short* __restrict__ vw) {
    const int tile = blockIdx.x;            // b*NKT + kt
    const float* kp = kg + (size_t)tile * 64 * DIM;
    const float* vp = vg + (size_t)tile * 64 * DIM;
    short* ko = kw + (size_t)tile * 4096;
    short* vo = vw + (size_t)tile * 4096;
    const int t = threadIdx.x;
#pragma unroll
    for (int i = 0; i < 4; ++i) {
        const int flat = i * 256 + t;
        const int key = flat >> 4, d0 = (flat & 15) * 4;
        const float4 kv = *(const float4*)(kp + (size_t)key * DIM + d0);
        uint2 kpk;
        kpk.x = pk2bf(kv.x, kv.y); kpk.y = pk2bf(kv.z, kv.w);
        *(uint2*)(ko + (((d0 >> 3) << 6) + key) * 8 + (d0 & 7)) = kpk;
        const float4 vv = *(const float4*)(vp + (size_t)key * DIM + d0);
        const int kc = key >> 3, jk = key & 7;
        vo[((kc << 6) + d0 + 0) * 8 + jk] = f2bf(vv.x);
        vo[((kc << 6) + d0 + 1) * 8 + jk] = f2bf(vv.y);
        vo[((kc << 6) + d0 + 2) * 8 + jk] = f2bf(vv.z);
        vo[((kc << 6) + d0 + 3) * 8 + jk] = f2bf(vv.w);
    }
}

template <bool WS>
__global__ __launch_bounds__(256, 2)
void attn_fwd(const float* __restrict__ qg, const float* __restrict__ kg,
              const float* __restrict__ vg, const int* __restrict__ mg,
              float* __restrict__ og, const short* __restrict__ kw,
              const short* __restrict__ vw) {
    __shared__ float Ob[2][32 * 65];   // per-qsub combine + transpose scratch
    __shared__ float Lb[2][32];

    const int t    = threadIdx.x;
    const int w    = t >> 6;        // wave 0..3
    const int L    = t & 63;
    const int q31  = L & 31;
    const int h    = L >> 5;        // lane half
    const int kh   = w & 1;         // key half of the 64-key tile
    const int qsub = w >> 1;        // q sub-tile (32 rows)

    // grid: b = id&7 (XCD affinity); ids x and x+256 -> adjacent qb
    const int id = blockIdx.x;
    const int b  = id & 7;
    const int j  = id >> 3;
    const int qb = 63 - 2 * (j & 31) - (j >> 5);
    const int qbase  = qb * 64;
    const int ntiles = qb + 1;

    const float* qp = qg + (size_t)b * SEQ * DIM;
    const float* kp = kg + (size_t)b * SEQ * DIM;
    const float* vp = vg + (size_t)b * SEQ * DIM;
    const int*   mp = mg + (size_t)b * SEQ;
    const short* kwb = WS ? kw + (size_t)b * NKT * 4096 : nullptr;
    const short* vwb = WS ? vw + (size_t)b * NKT * 4096 : nullptr;

    const int qrow = qbase + qsub * 32 + q31;   // this lane's q column
    const float qscale = 0.125f * 1.44269504088896340736f; // 1/sqrt(64)*log2e

    // Q B-fragments (32x32x16): B[k=16c+8h+jj][n=q31], scale folded
    bf16x8 Qf[4];
#pragma unroll
    for (int c = 0; c < 4; ++c) {
        const float* src = qp + (size_t)qrow * DIM + c * 16 + h * 8;
        float4 x = *(const float4*)src;
        float4 y = *(const float4*)(src + 4);
        x.x *= qscale; x.y *= qscale; x.z *= qscale; x.w *= qscale;
        y.x *= qscale; y.y *= qscale; y.z *= qscale; y.w *= qscale;
        Qf[c] = pack8(x, y);
    }

    float lsum = 0.0f;
    f32x16 Oacc[2];
#pragma unroll
    for (int nb = 0; nb < 2; ++nb)
#pragma unroll
        for (int r = 0; r < 16; ++r) Oacc[nb][r] = 0.0f;

    // ---- register-direct fragment loads for tile kt
    auto loadt = [&](bf16x8 (&Kd)[4], bf16x8 (&Vd)[4], int4 (&Md)[4], int kt) {
        if constexpr (WS) {
            const short* kb = kwb + (size_t)kt * 4096;
            const short* vb = vwb + (size_t)kt * 4096;
#pragma unroll
            for (int c = 0; c < 4; ++c)
                Kd[c] = *(const bf16x8*)&kb[(((2 * c + h) << 6) + kh * 32 + q31) * 8];
#pragma unroll
            for (int kk = 0; kk < 2; ++kk)
#pragma unroll
                for (int nb = 0; nb < 2; ++nb)
                    Vd[kk * 2 + nb] = *(const bf16x8*)&vb[(((4 * kh + 2 * kk + h) << 6) + nb * 32 + q31) * 8];
        } else {
            // fallback: gather from fp32 (correctness path)
#pragma unroll
            for (int c = 0; c < 4; ++c) {
                const float* src = kp + (size_t)(kt * 64 + kh * 32 + q31) * DIM + c * 16 + h * 8;
                Kd[c] = pack8(*(const float4*)src, *(const float4*)(src + 4));
            }
#pragma unroll
            for (int kk = 0; kk < 2; ++kk)
#pragma unroll
                for (int nb = 0; nb < 2; ++nb) {
                    bf16x8 f;
#pragma unroll
                    for (int jj = 0; jj < 8; ++jj)
                        f[jj] = f2bf(vp[(size_t)(kt * 64 + kh * 32 + 16 * kk + 8 * h + jj) * DIM + nb * 32 + q31]);
                    Vd[kk * 2 + nb] = f;
                }
        }
#pragma unroll
        for (int g = 0; g < 4; ++g)
            Md[g] = *(const int4*)&mp[kt * 64 + kh * 32 + 8 * g + 4 * h];
    };

    auto compute = [&](bf16x8 (&Kc)[4], bf16x8 (&Vc)[4], int4 (&Mc)[4], int kt) {
        // S^T = K @ Q^T : D[m=key_local][n=q], one 32x32 acc, 4 MFMAs over d
        f32x16 sa;
#pragma unroll
        for (int r = 0; r < 16; ++r) sa[r] = 0.0f;
#pragma unroll
        for (int c = 0; c < 4; ++c)
            sa = __builtin_amdgcn_mfma_f32_32x32x16_bf16(Kc[c], Qf[c], sa, 0, 0, 0);

        // mask + exp2 (fixed-ref softmax, clamp). row = 4h + e + 8g
        const bool diag = (kt == ntiles - 1);
        float p[16];
#pragma unroll
        for (int g = 0; g < 4; ++g) {
            const int mi[4] = {Mc[g].x, Mc[g].y, Mc[g].z, Mc[g].w};
#pragma unroll
            for (int e = 0; e < 4; ++e) {
                const int reg = g * 4 + e;
                float s = sa[reg];
                bool keep = (mi[e] != 0);
                if (diag) {
                    const int keyg = kt * 64 + kh * 32 + 4 * h + e + 8 * g;
                    keep = keep && (keyg <= qrow);
                }
                s = keep ? s : -1e30f;
                p[reg] = fast_exp2(fminf(s, 80.0f));
                lsum += p[reg];
            }
        }

        // P -> B-fragment via lane^32 exchange (rows 4h+{0..3} <-> 4(1-h)+{0..3})
        unsigned u[8], su[8];
#pragma unroll
        for (int i = 0; i < 8; ++i) u[i] = pk2bf(p[2 * i], p[2 * i + 1]);
#pragma unroll
        for (int i = 0; i < 8; ++i) su[i] = (unsigned)__shfl_xor((int)u[i], 32);
        int4 fi0 = h ? (int4){(int)su[2], (int)su[3], (int)u[2], (int)u[3]}
                     : (int4){(int)u[0], (int)u[1], (int)su[0], (int)su[1]};
        int4 fi1 = h ? (int4){(int)su[6], (int)su[7], (int)u[6], (int)u[7]}
                     : (int4){(int)u[4], (int)u[5], (int)su[4], (int)su[5]};
        bf16x8 pf0 = __builtin_bit_cast(bf16x8, fi0);
        bf16x8 pf1 = __builtin_bit_cast(bf16x8, fi1);

        // O^T += V^T @ P^T : D[m=d_local][n=q]
        Oacc[0] = __builtin_amdgcn_mfma_f32_32x32x16_bf16(Vc[0], pf0, Oacc[0], 0, 0, 0);
        Oacc[1] = __builtin_amdgcn_mfma_f32_32x32x16_bf16(Vc[1], pf0, Oacc[1], 0, 0, 0);
        Oacc[0] = __builtin_amdgcn_mfma_f32_32x32x16_bf16(Vc[2], pf1, Oacc[0], 0, 0, 0);
        Oacc[1] = __builtin_amdgcn_mfma_f32_32x32x16_bf16(Vc[3], pf1, Oacc[1], 0, 0, 0);
    };

    // ---- barrier-free main loop, register double-buffered
    bf16x8 K0[4], V0[4], K1[4], V1[4];
    int4 M0[4], M1[4];
    loadt(K0, V0, M0, 0);
    int kt = 0;
    for (;;) {
        if (kt + 1 < ntiles) loadt(K1, V1, M1, kt + 1);
        compute(K0, V0, M0, kt);
        if (++kt >= ntiles) break;
        if (kt + 1 < ntiles) loadt(K0, V0, M0, kt + 1);
        compute(K1, V1, M1, kt);
        if (++kt >= ntiles) break;
    }

    // ---- epilogue: combine key-halves, normalize, transpose, store
    lsum += __shfl_xor(lsum, 32);    // per-lane l over its kh keys, all 32 rows

    if (kh == 1) {
#pragma unroll
        for (int nb = 0; nb < 2; ++nb)
#pragma unroll
            for (int r = 0; r < 16; ++r)
                Ob[qsub][((nb * 16 + r) * 2 + h) * 32 + q31] = Oacc[nb][r];
        if (h == 0) Lb[qsub][q31] = lsum;
    }
    __syncthreads();
    if (kh == 0) {
        const float inv = 1.0f / (lsum + Lb[qsub][q31]);
#pragma unroll
        for (int nb = 0; nb < 2; ++nb)
#pragma unroll
            for (int r = 0; r < 16; ++r)
                Oacc[nb][r] = (Oacc[nb][r] + Ob[qsub][((nb * 16 + r) * 2 + h) * 32 + q31]) * inv;
        // transpose via padded LDS (stride 65 -> conflict-free), then coalesced store
#pragma unroll
        for (int nb = 0; nb < 2; ++nb)
#pragma unroll
            for (int g = 0; g < 4; ++g)
#pragma unroll
                for (int e = 0; e < 4; ++e) {
                    const int d = nb * 32 + 4 * h + 8 * g + e;
                    Ob[qsub][q31 * 65 + d] = Oacc[nb][g * 4 + e];
                }
        float* op = og + (size_t)b * SEQ * DIM;
#pragma unroll
        for (int i = 0; i < 8; ++i) {
            const int flat = i * 256 + (L << 2);
            const int row = flat >> 6, d = flat & 63;
            const float4 val = *(const float4*)&Ob[qsub][row * 65 + d];
            *(float4*)&op[(size_t)(qbase + qsub * 32 + row) * DIM + d] = val;
        }
    }
}

extern "C" void kernel_launch(void* const* d_in, const int* in_sizes, int n_in,
                              void* d_out, int out_size, void* d_ws, size_t ws_size,
                              hipStream_t stream) {
    (void)in_sizes; (void)n_in; (void)out_size;
    const float* q = (const float*)d_in[0];
    const float* k = (const float*)d_in[1];
    const float* v = (const float*)d_in[2];
    const int*   m = (const int*)d_in[3];
    float* o = (float*)d_out;
    const size_t need = (size_t)BATCH * NKT * 4096 * sizeof(short) * 2; // 8 MB
    if (ws_size >= need) {
        short* kw = (short*)d_ws;
        short* vw = kw + (size_t)BATCH * NKT * 4096;
        prep_kv<<<dim3(BATCH * NKT), 256, 0, stream>>>(k, v, kw, vw);
        attn_fwd<true><<<dim3(512), 256, 0, stream>>>(q, k, v, m, o, kw, vw);
    } else {
        attn_fwd<false><<<dim3(512), 256, 0, stream>>>(q, k, v, m, o, nullptr, nullptr);
    }
}

// Round 7
// 141.028 us; speedup vs baseline: 1.1442x; 1.1442x over previous
//
#include <hip/hip_runtime.h>

// Attention: B=8, N=4096, D=64, fp32 in/out, causal + padding mask.
// R7: R5's async-LDS double-buffered staging skeleton (1 barrier/tile,
//     global_load_lds from prep'd bf16 ws) + R6's compute core: 32x32x16
//     MFMA (2x FLOP per fragment byte), S^T orientation, fixed-ref log2
//     softmax (no cross-lane in loop), P->B-fragment via 8 shfl_xor(32).
//     4 waves/block, 64q x 64k tiles, epilogue merge aliases K/V LDS.

#define BATCH 8
#define SEQ   4096
#define DIM   64
#define NKT   (SEQ / 64)

typedef __attribute__((ext_vector_type(8)))  short bf16x8;
typedef __attribute__((ext_vector_type(16))) float f32x16;

__device__ inline short f2bf(float f) {
    unsigned u = __builtin_bit_cast(unsigned, f);
    u += 0x7FFFu + ((u >> 16) & 1u);   // RNE
    return (short)(u >> 16);
}
__device__ inline unsigned pk2bf(float a, float b) {
    unsigned ua = __builtin_bit_cast(unsigned, a) + 0x8000u;
    unsigned ub = __builtin_bit_cast(unsigned, b) + 0x8000u;
    return __builtin_amdgcn_perm(ub, ua, 0x07060302u);
}
__device__ inline float fast_exp2(float x) {
#if __has_builtin(__builtin_amdgcn_exp2f)
    return __builtin_amdgcn_exp2f(x);
#else
    return exp2f(x);
#endif
}
__device__ inline bf16x8 pack8(const float4& a, const float4& b) {
    bf16x8 r;
    r[0] = f2bf(a.x); r[1] = f2bf(a.y); r[2] = f2bf(a.z); r[3] = f2bf(a.w);
    r[4] = f2bf(b.x); r[5] = f2bf(b.y); r[6] = f2bf(b.z); r[7] = f2bf(b.w);
    return r;
}
__device__ inline void gl_lds16(const void* g, void* l) {
    __builtin_amdgcn_global_load_lds(
        (const __attribute__((address_space(1))) void*)g,
        (__attribute__((address_space(3))) void*)l, 16, 0, 0);
}

// ---- pre-pass: fp32 K,V -> bf16 tiles, MFMA-fragment order ----
// K tile: cell(dchunk 0..7, key 0..63) = dchunk*64+key, 8 shorts (d in chunk)
// V tile: cell(kchunk 0..7, d 0..63)  = kchunk*64+d,   8 shorts (key in chunk)
__global__ __launch_bounds__(256)
void prep_kv(const float* __restrict__ kg, const float* __restrict__ vg,
             short* __restrict__ kw, short* __restrict__ vw) {
    const int tile = blockIdx.x;            // b*NKT + kt
    const float* kp = kg + (size_t)tile * 64 * DIM;
    const float* vp = vg + (size_t)tile * 64 * DIM;
    short* ko = kw + (size_t)tile * 4096;
    short* vo = vw + (size_t)tile * 4096;
    const int t = threadIdx.x;
#pragma unroll
    for (int i = 0; i < 4; ++i) {
        const int flat = i * 256 + t;
        const int key = flat >> 4, d0 = (flat & 15) * 4;
        const float4 kv = *(const float4*)(kp + (size_t)key * DIM + d0);
        uint2 kpk;
        kpk.x = pk2bf(kv.x, kv.y); kpk.y = pk2bf(kv.z, kv.w);
        *(uint2*)(ko + (((d0 >> 3) << 6) + key) * 8 + (d0 & 7)) = kpk;
        const float4 vv = *(const float4*)(vp + (size_t)key * DIM + d0);
        const int kc = key >> 3, jk = key & 7;
        vo[((kc << 6) + d0 + 0) * 8 + jk] = f2bf(vv.x);
        vo[((kc << 6) + d0 + 1) * 8 + jk] = f2bf(vv.y);
        vo[((kc << 6) + d0 + 2) * 8 + jk] = f2bf(vv.z);
        vo[((kc << 6) + d0 + 3) * 8 + jk] = f2bf(vv.w);
    }
}

template <bool WS>
__global__ __launch_bounds__(256, 2)
void attn_fwd(const float* __restrict__ qg, const float* __restrict__ kg,
              const float* __restrict__ vg, const int* __restrict__ mg,
              float* __restrict__ og, const short* __restrict__ kw,
              const short* __restrict__ vw) {
    __shared__ __align__(16) char smem[33024];
    short* KbS = (short*)smem;             // [2][4096] shorts = 16384 B
    short* VbS = (short*)(smem + 16384);   // [2][4096] shorts = 16384 B
    float* Lb  = (float*)(smem + 32768);   // [2][32]
    float* ObF = (float*)smem;             // epilogue alias: [2][2080] f32

    const int t    = threadIdx.x;
    const int w    = t >> 6;        // wave 0..3
    const int L    = t & 63;
    const int q31  = L & 31;
    const int h    = L >> 5;
    const int kh   = w & 1;         // key half (32 keys)
    const int qsub = w >> 1;        // q sub-tile (32 rows)

    // b = id&7 (batch <-> XCD L2 affinity); adjacent j's pair long+short chains
    const int id = blockIdx.x;
    const int b  = id & 7;
    const int j  = id >> 3;
    const int qb = (j & 1) ? (j >> 1) : (63 - (j >> 1));
    const int qbase  = qb * 64;
    const int ntiles = qb + 1;

    const float* qp = qg + (size_t)b * SEQ * DIM;
    const float* kp = kg + (size_t)b * SEQ * DIM;
    const float* vp = vg + (size_t)b * SEQ * DIM;
    const int*   mp = mg + (size_t)b * SEQ;
    const short* kwb = WS ? kw + (size_t)b * NKT * 4096 : nullptr;
    const short* vwb = WS ? vw + (size_t)b * NKT * 4096 : nullptr;

    const int qrow = qbase + qsub * 32 + q31;   // lane's q column (S^T)
    const float qscale = 0.125f * 1.44269504088896340736f; // 1/sqrt(64)*log2e

    // Q B-fragments (32x32x16): B[k=16c+8h+jj][n=q31], scale folded
    bf16x8 Qf[4];
#pragma unroll
    for (int c = 0; c < 4; ++c) {
        const float* src = qp + (size_t)qrow * DIM + c * 16 + h * 8;
        float4 x = *(const float4*)src;
        float4 y = *(const float4*)(src + 4);
        x.x *= qscale; x.y *= qscale; x.z *= qscale; x.w *= qscale;
        y.x *= qscale; y.y *= qscale; y.z *= qscale; y.w *= qscale;
        Qf[c] = pack8(x, y);
    }

    // async stage tile kt into buffer bs: wave w covers shorts [w*1024, +1024)
    auto stage = [&](int bs, int kt) {
        const short* ks = kwb + (size_t)kt * 4096;
        const short* vs = vwb + (size_t)kt * 4096;
#pragma unroll
        for (int it = 0; it < 2; ++it) {
            const int off = (w << 10) + (it << 9);   // wave-uniform base
            gl_lds16(ks + off + (L << 3), KbS + bs * 4096 + off);
            gl_lds16(vs + off + (L << 3), VbS + bs * 4096 + off);
        }
    };

    float lsum = 0.0f;
    f32x16 Oacc[2];
#pragma unroll
    for (int nb = 0; nb < 2; ++nb)
#pragma unroll
        for (int r = 0; r < 16; ++r) Oacc[nb][r] = 0.0f;

    if constexpr (WS) stage(0, 0);

    for (int kt = 0; kt < ntiles; ++kt) {
        const int cur = WS ? (kt & 1) : 0;

        if constexpr (WS) {
            __syncthreads();   // drains stage(kt); prev reads of buf cur^1 done
            if (kt + 1 < ntiles) stage(cur ^ 1, kt + 1);
        } else {
            __syncthreads();
#pragma unroll
            for (int i = 0; i < 4; ++i) {
                const int flat = i * 256 + t;
                const int key = flat >> 4, d0 = (flat & 15) * 4;
                const float4 kv = *(const float4*)(kp + (size_t)(kt * 64 + key) * DIM + d0);
                uint2 kk;
                kk.x = pk2bf(kv.x, kv.y); kk.y = pk2bf(kv.z, kv.w);
                *(uint2*)&KbS[(((d0 >> 3) << 6) + key) * 8 + (d0 & 7)] = kk;
                const float4 vv = *(const float4*)(vp + (size_t)(kt * 64 + key) * DIM + d0);
                const int kc = key >> 3, jk = key & 7;
                VbS[((kc << 6) + d0 + 0) * 8 + jk] = f2bf(vv.x);
                VbS[((kc << 6) + d0 + 1) * 8 + jk] = f2bf(vv.y);
                VbS[((kc << 6) + d0 + 2) * 8 + jk] = f2bf(vv.z);
                VbS[((kc << 6) + d0 + 3) * 8 + jk] = f2bf(vv.w);
            }
            __syncthreads();
        }

        const short* Kt = KbS + cur * 4096;
        const short* Vt = VbS + cur * 4096;

        // mask int4 loads (L1-hot, independent of MFMAs -> latency overlapped)
        int4 Md[4];
#pragma unroll
        for (int g = 0; g < 4; ++g)
            Md[g] = *(const int4*)&mp[kt * 64 + kh * 32 + 8 * g + 4 * h];

        // ---- S^T = K @ Q^T : D[m=key_local][n=q], 4 MFMAs over d
        f32x16 sa;
#pragma unroll
        for (int r = 0; r < 16; ++r) sa[r] = 0.0f;
#pragma unroll
        for (int c = 0; c < 4; ++c) {
            bf16x8 kf = *(const bf16x8*)&Kt[(((2 * c + h) << 6) + kh * 32 + q31) * 8];
            sa = __builtin_amdgcn_mfma_f32_32x32x16_bf16(kf, Qf[c], sa, 0, 0, 0);
        }

        // ---- mask + exp2 (fixed-ref softmax, clamp). row = 4h + 8g + e
        const bool diag = (kt == ntiles - 1);
        float p[16];
#pragma unroll
        for (int g = 0; g < 4; ++g) {
            const int mi[4] = {Md[g].x, Md[g].y, Md[g].z, Md[g].w};
#pragma unroll
            for (int e = 0; e < 4; ++e) {
                const int reg = g * 4 + e;
                float s = sa[reg];
                bool keep = (mi[e] != 0);
                if (diag) {
                    const int keyg = kt * 64 + kh * 32 + 4 * h + 8 * g + e;
                    keep = keep && (keyg <= qrow);
                }
                s = keep ? s : -1e30f;
                p[reg] = fast_exp2(fminf(s, 80.0f));
                lsum += p[reg];
            }
        }

        // ---- P -> B-fragment via lane^32 exchange
        unsigned u[8], su[8];
#pragma unroll
        for (int i = 0; i < 8; ++i) u[i] = pk2bf(p[2 * i], p[2 * i + 1]);
#pragma unroll
        for (int i = 0; i < 8; ++i) su[i] = (unsigned)__shfl_xor((int)u[i], 32);
        int4 fi0 = h ? (int4){(int)su[2], (int)su[3], (int)u[2], (int)u[3]}
                     : (int4){(int)u[0], (int)u[1], (int)su[0], (int)su[1]};
        int4 fi1 = h ? (int4){(int)su[6], (int)su[7], (int)u[6], (int)u[7]}
                     : (int4){(int)u[4], (int)u[5], (int)su[4], (int)su[5]};
        bf16x8 pf0 = __builtin_bit_cast(bf16x8, fi0);
        bf16x8 pf1 = __builtin_bit_cast(bf16x8, fi1);

        // ---- O^T += V^T @ P^T : D[m=d_local][n=q]
#pragma unroll
        for (int kk = 0; kk < 2; ++kk) {
            const bf16x8 pf = kk ? pf1 : pf0;
#pragma unroll
            for (int nb = 0; nb < 2; ++nb) {
                bf16x8 vf = *(const bf16x8*)&Vt[(((4 * kh + 2 * kk + h) << 6) + nb * 32 + q31) * 8];
                Oacc[nb] = __builtin_amdgcn_mfma_f32_32x32x16_bf16(vf, pf, Oacc[nb], 0, 0, 0);
            }
        }
    }

    // ---- epilogue: combine key-halves, normalize, transpose, store
    lsum += __shfl_xor(lsum, 32);      // both h-halves of this kh's 32 keys

    __syncthreads();                    // K/V LDS reads done -> alias safe
    float* Ob = ObF + qsub * 2080;
    if (kh == 1) {
#pragma unroll
        for (int nb = 0; nb < 2; ++nb)
#pragma unroll
            for (int r = 0; r < 16; ++r)
                Ob[((nb * 16 + r) * 2 + h) * 32 + q31] = Oacc[nb][r];
        if (h == 0) Lb[qsub * 32 + q31] = lsum;
    }
    __syncthreads();
    if (kh == 0) {
        const float inv = 1.0f / (lsum + Lb[qsub * 32 + q31]);
#pragma unroll
        for (int nb = 0; nb < 2; ++nb)
#pragma unroll
            for (int r = 0; r < 16; ++r)
                Oacc[nb][r] = (Oacc[nb][r] + Ob[((nb * 16 + r) * 2 + h) * 32 + q31]) * inv;
        // transpose via padded LDS rows (stride 65), then coalesced f4 store
#pragma unroll
        for (int nb = 0; nb < 2; ++nb)
#pragma unroll
            for (int g = 0; g < 4; ++g)
#pragma unroll
                for (int e = 0; e < 4; ++e) {
                    const int d = nb * 32 + 4 * h + 8 * g + e;
                    Ob[q31 * 65 + d] = Oacc[nb][g * 4 + e];
                }
        float* op = og + (size_t)b * SEQ * DIM;
#pragma unroll
        for (int i = 0; i < 8; ++i) {
            const int flat = i * 256 + (L << 2);
            const int row = flat >> 6, d = flat & 63;
            const float4 val = *(const float4*)&Ob[row * 65 + d];
            *(float4*)&op[(size_t)(qbase + qsub * 32 + row) * DIM + d] = val;
        }
    }
}

extern "C" void kernel_launch(void* const* d_in, const int* in_sizes, int n_in,
                              void* d_out, int out_size, void* d_ws, size_t ws_size,
                              hipStream_t stream) {
    (void)in_sizes; (void)n_in; (void)out_size;
    const float* q = (const float*)d_in[0];
    const float* k = (const float*)d_in[1];
    const float* v = (const float*)d_in[2];
    const int*   m = (const int*)d_in[3];
    float* o = (float*)d_out;
    const size_t need = (size_t)BATCH * NKT * 4096 * sizeof(short) * 2; // 8 MB
    if (ws_size >= need) {
        short* kw = (short*)d_ws;
        short* vw = kw + (size_t)BATCH * NKT * 4096;
        prep_kv<<<dim3(BATCH * NKT), 256, 0, stream>>>(k, v, kw, vw);
        attn_fwd<true><<<dim3(512), 256, 0, stream>>>(q, k, v, m, o, kw, vw);
    } else {
        attn_fwd<false><<<dim3(512), 256, 0, stream>>>(q, k, v, m, o, nullptr, nullptr);
    }
}